// Round 14
// baseline (13354.579 us; speedup 1.0000x reference)
//
#include <hip/hip_runtime.h>
#include <stdint.h>

// LatticeLSTM on MI355X, round 14.
// R11 core (proven: 1885us lattice, 682 hops x 2.76us) + proj FUSION:
// proj_fused kernel deleted; waves 0-2 compute each step's Xg/Xa/Wgx chunks
// JIT during the gather phase (they were idle at the barrier while wave 3
// polls ~2us). Direct L2 reads of x/emb/Wih/aWih/wWih column slices --
// (k,gate) cache lines are fully reused across the WG's 16 columns.
// Sync protocol byte-identical to R11. R12/R13 ping-pong abandoned
// (compiler register-rename hazard on split issue/wait asm).

#define T_LEN 512
#define H_DIM 512
#define G3    1536
#define D_IN  256
#define NWG   32
#define NT    256
#define CH    16
#define SENTU 0xFFFFFFFFu
#define WDOG  (1 << 17)
#define SCOPE_AGENT __HIP_MEMORY_SCOPE_AGENT

typedef unsigned u32x4v __attribute__((ext_vector_type(4)));

__device__ __forceinline__ float sigf(float x) { return 1.0f / (1.0f + __expf(-x)); }
__device__ __forceinline__ float tanhfast(float x) {
  x = fminf(fmaxf(x, -15.f), 15.f);
  float t = __expf(2.f * x);
  return (t - 1.f) / (t + 1.f);
}

// two pipelined 16B agent-scope loads, one vmcnt window (R11-proven)
__device__ __forceinline__ void mload16x2(const float* p0, const float* p1,
                                          u32x4v& a, u32x4v& b) {
  asm volatile("global_load_dwordx4 %0, %2, off sc1\n\t"
               "global_load_dwordx4 %1, %3, off sc1\n\t"
               "s_waitcnt vmcnt(0)"
               : "=&v"(a), "=&v"(b) : "v"(p0), "v"(p1) : "memory");
}
__device__ __forceinline__ bool sent4(u32x4v v) {
  return v.x == SENTU || v.y == SENTU || v.z == SENTU || v.w == SENTU;
}

#define REP32(F) F(0) F(1) F(2) F(3) F(4) F(5) F(6) F(7) F(8) F(9) F(10) F(11) \
                 F(12) F(13) F(14) F(15) F(16) F(17) F(18) F(19) F(20) F(21) F(22) \
                 F(23) F(24) F(25) F(26) F(27) F(28) F(29) F(30) F(31)

#define DECLW(u) float4 wA##u = {0.f,0.f,0.f,0.f}, wB##u = {0.f,0.f,0.f,0.f};

#define LDA1(u) wA##u = make_float4(srcA[(size_t)(ks4 + u*16 + 0) * ldA + gA],  \
                                    srcA[(size_t)(ks4 + u*16 + 1) * ldA + gA],  \
                                    srcA[(size_t)(ks4 + u*16 + 2) * ldA + gA],  \
                                    srcA[(size_t)(ks4 + u*16 + 3) * ldA + gA]);
#define LDB1(u) wB##u = make_float4(srcB[(size_t)(ks4 + u*16 + 0) * (size_t)G3 + gA], \
                                    srcB[(size_t)(ks4 + u*16 + 1) * (size_t)G3 + gA], \
                                    srcB[(size_t)(ks4 + u*16 + 2) * (size_t)G3 + gA], \
                                    srcB[(size_t)(ks4 + u*16 + 3) * (size_t)G3 + gA]);

#define DOTA1(u) { float4 hv = *(const float4*)&vecp[ks4 + u*16];                \
                   q.x += hv.x*wA##u.x; q.y += hv.y*wA##u.y;                     \
                   q.z += hv.z*wA##u.z; q.w += hv.w*wA##u.w; }
#define DOTB1(u) { float4 hv = *(const float4*)&vecp[ks4 + u*16];                \
                   q.x += hv.x*wB##u.x; q.y += hv.y*wB##u.y;                     \
                   q.z += hv.z*wB##u.z; q.w += hv.w*wB##u.w; }
#define DOT_FIN(dst, g) { float acc = (q.x + q.y) + (q.z + q.w);                 \
                          acc += __shfl_down(acc, 2); acc += __shfl_down(acc, 1);\
                          if (((g) & 3) == 0) dst = acc; }

#define ALPHA_DOT(k)  do {                                                       \
    if (l_cm[e * 2 + (k)]) {                                                     \
      asm volatile("s_waitcnt lgkmcnt(0)" ::: "memory");                         \
      __builtin_amdgcn_sched_barrier(0);                                         \
      const float* vecp = &cins[par][k][0];                                      \
      float4 q = {0.f, 0.f, 0.f, 0.f};                                           \
      REP32(DOTA1)                                                               \
      DOT_FIN(ds_a[(k) * CH + dcol], lane)                                       \
    }                                                                            \
  } while (0)

// JIT K=256 dot: vector base vr (consecutive), weight column base wc (stride G3/512)
__device__ __forceinline__ float jitdot(const float* vr, const float* wc, int ldw) {
  float a0 = 0.f, a1 = 0.f, a2 = 0.f, a3 = 0.f;
#pragma unroll
  for (int i = 0; i < 16; ++i) {
    float4 xv = *(const float4*)(vr + i * 4);
    const float* wp = wc + (size_t)(i * 4) * ldw;
    a0 += xv.x * wp[0];
    a1 += xv.y * wp[ldw];
    a2 += xv.z * wp[2 * ldw];
    a3 += xv.w * wp[3 * ldw];
  }
  return (a0 + a1) + (a2 + a3);
}
// reduce over the 4-lane ks group; valid at ks==0
__device__ __forceinline__ float red4f(float acc) {
  acc += __shfl_down(acc, 2);
  acc += __shfl_down(acc, 1);
  return acc;
}

// ---------------- sequential lattice scan + fused JIT projections ----------------
__global__ __attribute__((amdgpu_flat_work_group_size(NT, NT), amdgpu_waves_per_eu(1, 1)))
void lattice_seq(
    const float* __restrict__ x,     // (1,T,D)
    const float* __restrict__ emb,   // (V,E)
    const float* __restrict__ Wih,   // D x 1536
    const float* __restrict__ bias,  // 1536
    const float* __restrict__ aWih,  // D x 512
    const float* __restrict__ ab,    // 512
    const float* __restrict__ wWih,  // E x 1536
    const float* __restrict__ wb,    // 1536
    const float* __restrict__ Whh, const float* __restrict__ aWhh, const float* __restrict__ wWhh,
    const int* __restrict__ prod_word, const int* __restrict__ prod_mask,
    const int* __restrict__ prod_dest, const int* __restrict__ cons_idx,
    const int* __restrict__ cons_mask,
    float* __restrict__ Hbuf,     // T x 512, memset 0xFF (sentinel)
    float* __restrict__ store,    // (M+1) x 512, memset 0xFF (sentinel)
    float* __restrict__ out)      // hs at [0,T*H), cs at [T*H, 2*T*H)
{
  const int tid = threadIdx.x;
  const int w = blockIdx.x;
  const int j0 = w * CH;
  float* outh = out;
  float* outc = out + (size_t)T_LEN * H_DIM;

  __shared__ float h1s[H_DIM];
  __shared__ float prevc1[CH];
  __shared__ float ds_g[3 * CH];
  __shared__ float ds_wg[3 * CH];
  __shared__ float ds_a[2 * CH];
  __shared__ float ds_xg[3 * CH];    // JIT: Xg chunk (bias folded)
  __shared__ float ds_xa[CH];        // JIT: Xa chunk (ab folded)
  __shared__ float ds_wgx[2][3 * CH];// JIT: Wgx rows for words @ p (wb folded)
  __shared__ float cins[2][2][H_DIM];
  __shared__ int l_pm[T_LEN * 2], l_pd[T_LEN * 2], l_ci[T_LEN * 2], l_cm[T_LEN * 2];
  __shared__ int l_pw[T_LEN * 2];

  for (int i = tid; i < T_LEN * 2; i += NT) {
    l_pm[i] = prod_mask[i];
    l_pd[i] = prod_dest[i];
    l_ci[i] = cons_idx[i];
    l_cm[i] = cons_mask[i];
    l_pw[i] = prod_word[i];
  }

  // roles: tid<192 -> Whh (wA) + wWhh (wB), 48 cols x 4-deep, + JIT proj;
  //        tid>=192 (wave 3) -> aWhh (wA), 16 cols x 4-deep; sole poller.
  int dcol, ks4;
  if (tid < 192) { dcol = tid >> 2; ks4 = (tid & 3) << 2; }
  else { int lane = tid - 192; dcol = lane >> 2; ks4 = (lane & 3) << 2; }

  REP32(DECLW)
  int gXg = 0, gXa = -1;
  float bXg = 0.f, bWb = 0.f, bXa = 0.f;
  if (tid < 192) {
    const float* srcA = Whh;
    const float* srcB = wWhh;
    const size_t ldA = G3;
    const int gA = (dcol >> 4) * 512 + j0 + (dcol & 15);
    REP32(LDA1)
    REP32(LDB1)
    gXg = gA;                 // same column index into Wih/wWih/bias/wb
    bXg = bias[gXg];
    bWb = wb[gXg];
    if (dcol < 16) { gXa = j0 + dcol; bXa = ab[gXa]; }
  } else {
    const float* srcA = aWhh;
    const size_t ldA = H_DIM;
    const int gA = j0 + dcol;
    REP32(LDA1)
  }
  const int jks = (tid & 3) * 64;   // JIT depth offset (64 of 256)

  ((float2*)h1s)[tid] = make_float2(0.f, 0.f);
  if (tid < CH) prevc1[tid] = 0.f;
  __syncthreads();

  for (int e = 0; e < T_LEN; ++e) {
    const int p = e - 1;
    const bool prodp = (p >= 0) && ((l_pm[p * 2] | l_pm[p * 2 + 1]) != 0);
    const bool conse = (l_cm[e * 2] | l_cm[e * 2 + 1]) != 0;
    const int par = e & 1;

    // freshness: a consumed row is fresh iff produced at step p
    bool fresh0 = false, fresh1 = false;
    if (conse && prodp) {
      int m0 = l_ci[e * 2], m1 = l_ci[e * 2 + 1];
      fresh0 = (l_pm[p * 2] && l_pd[p * 2] == m0) || (l_pm[p * 2 + 1] && l_pd[p * 2 + 1] == m0);
      fresh1 = (l_pm[p * 2] && l_pd[p * 2] == m1) || (l_pm[p * 2 + 1] && l_pd[p * 2 + 1] == m1);
    }

    // ======== JIT projections on waves 0-2 (overlapped with wave-3 poll) ========
    if (tid < 192) {
      const float* xr = x + (size_t)e * D_IN + jks;
      float a = jitdot(xr, Wih + (size_t)jks * G3 + gXg, G3);
      a = red4f(a);
      if ((tid & 3) == 0) ds_xg[dcol] = a + bXg;
      if (gXa >= 0) {
        float a2 = jitdot(xr, aWih + (size_t)jks * H_DIM + gXa, H_DIM);
        a2 = red4f(a2);
        if ((tid & 3) == 0) ds_xa[dcol] = a2 + bXa;
      }
      if (prodp) {
#pragma unroll
        for (int k = 0; k < 2; ++k) {
          const int r = p * 2 + k;
          const float* er = emb + (size_t)l_pw[r] * D_IN + jks;
          float a3 = jitdot(er, wWih + (size_t)jks * G3 + gXg, G3);
          a3 = red4f(a3);
          if ((tid & 3) == 0) ds_wgx[k][dcol] = a3 + bWb;
        }
      }
    }

    // ======== wave 3: THE gather phase (sole remote reader, R11-proven) ========
    if (tid >= 192) {
      const int lane = tid - 192;
      int sA = -1, sB = -1;
      if (conse) {
        if (l_cm[e * 2] && !fresh0) sA = 0;
        if (l_cm[e * 2 + 1] && !fresh1) { if (sA < 0) sA = 1; else sB = 1; }
      }
      if (e > 0) {
        const float* hrow = Hbuf + (size_t)p * H_DIM;
        u32x4v a, b;
        int gd = 0;
        do { mload16x2(hrow + lane * 4, hrow + 256 + lane * 4, a, b); }
        while ((sent4(a) || sent4(b)) && ++gd < WDOG);
        *(u32x4v*)&h1s[lane * 4] = a;
        *(u32x4v*)&h1s[256 + lane * 4] = b;
      }
      // stale rows: available since >=2 steps; usually 1 attempt
      for (int k = 0; k < 2; ++k) {
        int sk = (k == 0) ? sA : sB;
        if (sk >= 0) {
          const float* srow = store + (size_t)l_ci[e * 2 + sk] * H_DIM;
          u32x4v s0, s1;
          int gd = 0;
          do { mload16x2(srow + lane * 4, srow + 256 + lane * 4, s0, s1); }
          while ((sent4(s0) || sent4(s1)) && ++gd < WDOG);
          *(u32x4v*)&cins[par][sk][lane * 4] = s0;
          *(u32x4v*)&cins[par][sk][256 + lane * 4] = s1;
        }
      }
    }
    __syncthreads();  // syncA: h1s + stale cins + JIT ds_xg/ds_xa/ds_wgx ready

    if (prodp) {
      // wgates first: they gate the ct -> fresh-alpha chain
      if (tid < 192) {
        const float* vecp = h1s;
        float4 q = {0.f, 0.f, 0.f, 0.f};
        REP32(DOTB1)
        DOT_FIN(ds_wg[dcol], tid)
      }
      __syncthreads();  // s1a: ds_wg ready
      if (tid < 192) {
        const float* vecp = h1s;
        float4 q = {0.f, 0.f, 0.f, 0.f};
        REP32(DOTA1)
        DOT_FIN(ds_g[dcol], tid)
      } else {
        const int lane = tid - 192;
        if (lane < 32) {  // finalize + publish word cells for words starting at p
          int k = lane >> 4, jj = lane & 15, r = p * 2 + k;
          if (l_pm[r]) {
            float f2 = ds_wgx[k][jj]      + ds_wg[jj];
            float i2 = ds_wgx[k][16 + jj] + ds_wg[16 + jj];
            float g2 = ds_wgx[k][32 + jj] + ds_wg[32 + jj];
            float ct = sigf(f2) * prevc1[jj] + sigf(i2) * tanhfast(g2);
            __hip_atomic_store(&store[(size_t)l_pd[r] * H_DIM + j0 + jj], ct,
                               __ATOMIC_RELAXED, SCOPE_AGENT);
          }
        }
      }
      __syncthreads();  // s1b: ds_g ready; ct stores issued
      if (conse && tid >= 192) {
        const int lane = tid - 192;
        for (int k = 0; k < 2; ++k) {  // fresh rows: poll the just-published ct
          bool fr = (k == 0) ? fresh0 : fresh1;
          if (l_cm[e * 2 + k] && fr) {
            const float* srow = store + (size_t)l_ci[e * 2 + k] * H_DIM;
            u32x4v s0, s1;
            int gd = 0;
            do { mload16x2(srow + lane * 4, srow + 256 + lane * 4, s0, s1); }
            while ((sent4(s0) || sent4(s1)) && ++gd < WDOG);
            *(u32x4v*)&cins[par][k][lane * 4] = s0;
            *(u32x4v*)&cins[par][k][256 + lane * 4] = s1;
          }
        }
        ALPHA_DOT(0);
        ALPHA_DOT(1);
      }
      __syncthreads();  // s2: ds_a + cins ready
    } else {
      if (tid < 192) {
        const float* vecp = h1s;
        float4 q = {0.f, 0.f, 0.f, 0.f};
        REP32(DOTA1)
        DOT_FIN(ds_g[dcol], tid)
      } else if (conse) {
        const int lane = tid - 192;
        ALPHA_DOT(0);
        ALPHA_DOT(1);
      }
      __syncthreads();  // sync1: ds_g (+ds_a) ready
    }

    // ---- elementwise combine for owned H-chunk (wave 0, lanes 0..15)
    if (tid < 16) {
      int j = j0 + tid;
      float ipre = ds_xg[tid]      + ds_g[tid];
      float opre = ds_xg[16 + tid] + ds_g[16 + tid];
      float gpre = ds_xg[32 + tid] + ds_g[32 + tid];
      float iv = sigf(ipre), ov = sigf(opre), gv = tanhfast(gpre);
      float c1;
      if (conse) {
        float ei = __expf(iv);
        float asum = ei, csum = gv * ei;
#pragma unroll
        for (int k = 0; k < 2; ++k) {
          if (l_cm[e * 2 + k]) {
            float apre = ds_xa[tid] + ds_a[k * CH + tid];
            float al = __expf(sigf(apre));
            asum += al;
            csum += cins[par][k][j] * al;
          }
        }
        c1 = csum / asum;
      } else {
        c1 = (1.f - iv) * prevc1[tid] + iv * gv;
      }
      float h1 = ov * tanhfast(c1);
      prevc1[tid] = c1;
      // publish h FIRST (it gates every other WG), then output stores
      __hip_atomic_store(&Hbuf[(size_t)e * H_DIM + j], h1, __ATOMIC_RELAXED, SCOPE_AGENT);
      outh[(size_t)e * H_DIM + j] = h1;
      outc[(size_t)e * H_DIM + j] = c1;
    }
    // no end-of-step barrier: next step's poll gates everyone on h(e)
  }
}

extern "C" void kernel_launch(void* const* d_in, const int* in_sizes, int n_in,
                              void* d_out, int out_size, void* d_ws, size_t ws_size,
                              hipStream_t stream) {
  const float* x    = (const float*)d_in[0];
  const float* emb  = (const float*)d_in[1];
  const float* Wih  = (const float*)d_in[2];
  const float* Whh  = (const float*)d_in[3];
  const float* bias = (const float*)d_in[4];
  const float* aWih = (const float*)d_in[5];
  const float* aWhh = (const float*)d_in[6];
  const float* ab   = (const float*)d_in[7];
  const float* wWih = (const float*)d_in[8];
  const float* wWhh = (const float*)d_in[9];
  const float* wb   = (const float*)d_in[10];
  const int* prod_word = (const int*)d_in[11];
  const int* prod_dest = (const int*)d_in[12];
  const int* prod_mask = (const int*)d_in[13];
  const int* cons_idx  = (const int*)d_in[14];
  const int* cons_mask = (const int*)d_in[15];

  float* ws    = (float*)d_ws;
  float* Hbuf  = ws;                          // 512*512   (sentinel)
  float* store = Hbuf + 512 * 512;            // 341*512   (sentinel)
  size_t need = ((size_t)512 * 512 + 341 * 512) * 4;
  if (ws_size < need) return;

  // re-poison sentinel regions every launch (graph-replay deterministic)
  hipMemsetAsync(Hbuf, 0xFF, (512 * 512 + 341 * 512) * sizeof(float), stream);

  lattice_seq<<<dim3(NWG), dim3(NT), 0, stream>>>(
      x, emb, Wih, bias, aWih, ab, wWih, wb,
      Whh, aWhh, wWhh,
      prod_word, prod_mask, prod_dest, cons_idx, cons_mask,
      Hbuf, store, (float*)d_out);
}

// Round 15
// 2152.510 us; speedup vs baseline: 6.2042x; 6.2042x over previous
//
#include <hip/hip_runtime.h>
#include <stdint.h>

// LatticeLSTM on MI355X, round 15.
// R11 lattice core (proven 1885us; 682 hops x 2.76us) + proj fused at the
// BLOCK level: one dispatch, blocks 0-31 = lattice (register-identical to
// R11 -- R14 showed waves 0-2 are at the 512-reg unified VGPR/AGPR budget,
// so NOTHING is added to their live state), blocks 32-351 = proj_fused's
// exact per-block work with agent-scope stores, then exit.
// Lattice reads Xg/Xa/Wgx via sentinel polls (single-window asm load+wait,
// the R11-proven pattern), hidden under wave 3's h-poll. Producers never
// wait -> deadlock-free; all polls watchdogged -> worst case fast NaN.

#define T_LEN 512
#define H_DIM 512
#define G3    1536
#define NWG   32
#define NPRJ  320
#define NT    256
#define CH    16
#define SENTU 0xFFFFFFFFu
#define WDOG  (1 << 17)
#define SCOPE_AGENT __HIP_MEMORY_SCOPE_AGENT

typedef unsigned u32x4v __attribute__((ext_vector_type(4)));

__device__ __forceinline__ float sigf(float x) { return 1.0f / (1.0f + __expf(-x)); }
__device__ __forceinline__ float tanhfast(float x) {
  x = fminf(fmaxf(x, -15.f), 15.f);
  float t = __expf(2.f * x);
  return (t - 1.f) / (t + 1.f);
}

// two pipelined 16B agent-scope loads, one vmcnt window (R11-proven)
__device__ __forceinline__ void mload16x2(const float* p0, const float* p1,
                                          u32x4v& a, u32x4v& b) {
  asm volatile("global_load_dwordx4 %0, %2, off sc1\n\t"
               "global_load_dwordx4 %1, %3, off sc1\n\t"
               "s_waitcnt vmcnt(0)"
               : "=&v"(a), "=&v"(b) : "v"(p0), "v"(p1) : "memory");
}
__device__ __forceinline__ bool sent4(u32x4v v) {
  return v.x == SENTU || v.y == SENTU || v.z == SENTU || v.w == SENTU;
}

// sentinel-poll N scalar dwords in ONE issue+wait window (no split hazard)
#define POLL4(v0, v1, v2, v3, p0, p1, p2, p3, need) do {                         \
    int gd_ = 0; bool ok_;                                                       \
    do {                                                                         \
      asm volatile("global_load_dword %0, %4, off sc1\n\t"                       \
                   "global_load_dword %1, %5, off sc1\n\t"                       \
                   "global_load_dword %2, %6, off sc1\n\t"                       \
                   "global_load_dword %3, %7, off sc1\n\t"                       \
                   "s_waitcnt vmcnt(0)"                                          \
                   : "=&v"(v0), "=&v"(v1), "=&v"(v2), "=&v"(v3)                  \
                   : "v"(p0), "v"(p1), "v"(p2), "v"(p3) : "memory");             \
      ok_ = !(need) || (v0 != SENTU && v1 != SENTU && v2 != SENTU && v3 != SENTU);\
    } while (!__all(ok_) && ++gd_ < WDOG);                                       \
  } while (0)

#define POLL3(v0, v1, v2, p0, p1, p2, need) do {                                 \
    int gd_ = 0; bool ok_;                                                       \
    do {                                                                         \
      asm volatile("global_load_dword %0, %3, off sc1\n\t"                       \
                   "global_load_dword %1, %4, off sc1\n\t"                       \
                   "global_load_dword %2, %5, off sc1\n\t"                       \
                   "s_waitcnt vmcnt(0)"                                          \
                   : "=&v"(v0), "=&v"(v1), "=&v"(v2)                             \
                   : "v"(p0), "v"(p1), "v"(p2) : "memory");                      \
      ok_ = !(need) || (v0 != SENTU && v1 != SENTU && v2 != SENTU);              \
    } while (!__all(ok_) && ++gd_ < WDOG);                                       \
  } while (0)

#define REP32(F) F(0) F(1) F(2) F(3) F(4) F(5) F(6) F(7) F(8) F(9) F(10) F(11) \
                 F(12) F(13) F(14) F(15) F(16) F(17) F(18) F(19) F(20) F(21) F(22) \
                 F(23) F(24) F(25) F(26) F(27) F(28) F(29) F(30) F(31)

#define DECLW(u) float4 wA##u = {0.f,0.f,0.f,0.f}, wB##u = {0.f,0.f,0.f,0.f};

#define LDA1(u) wA##u = make_float4(srcA[(size_t)(ks4 + u*16 + 0) * ldA + gA],  \
                                    srcA[(size_t)(ks4 + u*16 + 1) * ldA + gA],  \
                                    srcA[(size_t)(ks4 + u*16 + 2) * ldA + gA],  \
                                    srcA[(size_t)(ks4 + u*16 + 3) * ldA + gA]);
#define LDB1(u) wB##u = make_float4(srcB[(size_t)(ks4 + u*16 + 0) * (size_t)G3 + gA], \
                                    srcB[(size_t)(ks4 + u*16 + 1) * (size_t)G3 + gA], \
                                    srcB[(size_t)(ks4 + u*16 + 2) * (size_t)G3 + gA], \
                                    srcB[(size_t)(ks4 + u*16 + 3) * (size_t)G3 + gA]);

#define DOTA1(u) { float4 hv = *(const float4*)&vecp[ks4 + u*16];                \
                   q.x += hv.x*wA##u.x; q.y += hv.y*wA##u.y;                     \
                   q.z += hv.z*wA##u.z; q.w += hv.w*wA##u.w; }
#define DOTB1(u) { float4 hv = *(const float4*)&vecp[ks4 + u*16];                \
                   q.x += hv.x*wB##u.x; q.y += hv.y*wB##u.y;                     \
                   q.z += hv.z*wB##u.z; q.w += hv.w*wB##u.w; }
#define DOT_FIN(dst, g) { float acc = (q.x + q.y) + (q.z + q.w);                 \
                          acc += __shfl_down(acc, 2); acc += __shfl_down(acc, 1);\
                          if (((g) & 3) == 0) dst = acc; }

#define ALPHA_DOT(k)  do {                                                       \
    if (l_cm[e * 2 + (k)]) {                                                     \
      asm volatile("s_waitcnt lgkmcnt(0)" ::: "memory");                         \
      __builtin_amdgcn_sched_barrier(0);                                         \
      const float* vecp = &cins[par][k][0];                                      \
      float4 q = {0.f, 0.f, 0.f, 0.f};                                           \
      REP32(DOTA1)                                                               \
      DOT_FIN(ds_a[(k) * CH + dcol], lane)                                       \
    }                                                                            \
  } while (0)

// ---------------- fused mega-kernel ----------------
__global__ __attribute__((amdgpu_flat_work_group_size(NT, NT), amdgpu_waves_per_eu(1, 1)))
void fused_all(
    const float* __restrict__ x,     // (1,T,D)
    const float* __restrict__ emb,   // (V,E)
    const float* __restrict__ Wih, const float* __restrict__ bias,
    const float* __restrict__ aWih, const float* __restrict__ ab,
    const float* __restrict__ wWih, const float* __restrict__ wb,
    const float* __restrict__ Whh, const float* __restrict__ aWhh, const float* __restrict__ wWhh,
    const int* __restrict__ prod_word, const int* __restrict__ prod_mask,
    const int* __restrict__ prod_dest, const int* __restrict__ cons_idx,
    const int* __restrict__ cons_mask,
    float* __restrict__ Xg,       // T x 1536 (sentinel-synced, poisoned)
    float* __restrict__ Xa,       // T x 512
    float* __restrict__ Wgx,      // (T*2) x 1536
    float* __restrict__ Hbuf,     // T x 512
    float* __restrict__ store,    // (M+1) x 512
    float* __restrict__ out)      // hs at [0,T*H), cs at [T*H, 2*T*H)
{
  const int tid = threadIdx.x;

  __shared__ float As[32][256];          // proj path only (LDS summed w/ lattice; 1 blk/CU anyway)
  __shared__ float h1s[H_DIM];
  __shared__ float prevc1[CH];
  __shared__ float ds_g[3 * CH];
  __shared__ float ds_wg[3 * CH];
  __shared__ float ds_a[2 * CH];
  __shared__ float cins[2][2][H_DIM];
  __shared__ int l_pm[T_LEN * 2], l_pd[T_LEN * 2], l_ci[T_LEN * 2], l_cm[T_LEN * 2];

  // ================= producer path: blocks [NWG, NWG+NPRJ) =================
  if (blockIdx.x >= NWG) {
    const int b = blockIdx.x - NWG;
    const float *A, *W, *bi;
    float* o;
    const int* gather = nullptr;
    int rt, N, cb;
    if (b < 96)       { A = x;   W = Wih;  bi = bias; o = Xg;  N = 1536; rt = (b / 6) * 32;        cb = (b % 6) * 256; }
    else if (b < 128) { int bb = b - 96;  A = x;   W = aWih; bi = ab; o = Xa;  N = 512;  rt = (bb / 2) * 32; cb = (bb % 2) * 256; }
    else              { int bb = b - 128; A = emb; W = wWih; bi = wb; o = Wgx; N = 1536; gather = prod_word; rt = (bb / 6) * 32; cb = (bb % 6) * 256; }
    for (int rr = 0; rr < 32; ++rr) {
      int r = rt + rr;
      int src = gather ? gather[r] : r;
      As[rr][tid] = A[(size_t)src * 256 + tid];
    }
    __syncthreads();
    const int c = cb + tid;
    float acc[32];
#pragma unroll
    for (int rr = 0; rr < 32; ++rr) acc[rr] = 0.f;
#pragma unroll 4
    for (int k = 0; k < 256; ++k) {
      float wv = W[(size_t)k * N + c];
#pragma unroll
      for (int rr = 0; rr < 32; ++rr) acc[rr] += As[rr][k] * wv;
    }
    float bv = bi[c];
    for (int rr = 0; rr < 32; ++rr)
      __hip_atomic_store(&o[(size_t)(rt + rr) * N + c], acc[rr] + bv,
                         __ATOMIC_RELAXED, SCOPE_AGENT);  // MALL-visible (R8/R9 lesson)
    return;
  }

  // ================= lattice path: blocks [0, NWG) -- R11 core =================
  const int w = blockIdx.x;
  const int j0 = w * CH;
  float* outh = out;
  float* outc = out + (size_t)T_LEN * H_DIM;

  for (int i = tid; i < T_LEN * 2; i += NT) {
    l_pm[i] = prod_mask[i];
    l_pd[i] = prod_dest[i];
    l_ci[i] = cons_idx[i];
    l_cm[i] = cons_mask[i];
  }

  // roles: tid<192 -> Whh (wA) + wWhh (wB), 48 cols x 4-deep;
  //        tid>=192 (wave 3) -> aWhh (wA), 16 cols x 4-deep; sole remote poller.
  int dcol, ks4;
  if (tid < 192) { dcol = tid >> 2; ks4 = (tid & 3) << 2; }
  else { int lane = tid - 192; dcol = lane >> 2; ks4 = (lane & 3) << 2; }

  REP32(DECLW)
  if (tid < 192) {
    const float* srcA = Whh;
    const float* srcB = wWhh;
    const size_t ldA = G3;
    const int gA = (dcol >> 4) * 512 + j0 + (dcol & 15);
    REP32(LDA1)
    REP32(LDB1)
  } else {
    const float* srcA = aWhh;
    const size_t ldA = H_DIM;
    const int gA = j0 + dcol;
    REP32(LDA1)
  }

  ((float2*)h1s)[tid] = make_float2(0.f, 0.f);
  if (tid < CH) prevc1[tid] = 0.f;
  __syncthreads();

  for (int e = 0; e < T_LEN; ++e) {
    const int p = e - 1;
    const bool prodp = (p >= 0) && ((l_pm[p * 2] | l_pm[p * 2 + 1]) != 0);
    const bool conse = (l_cm[e * 2] | l_cm[e * 2 + 1]) != 0;
    const int par = e & 1;

    // freshness: a consumed row is fresh iff produced at step p
    bool fresh0 = false, fresh1 = false;
    if (conse && prodp) {
      int m0 = l_ci[e * 2], m1 = l_ci[e * 2 + 1];
      fresh0 = (l_pm[p * 2] && l_pd[p * 2] == m0) || (l_pm[p * 2 + 1] && l_pd[p * 2 + 1] == m0);
      fresh1 = (l_pm[p * 2] && l_pd[p * 2] == m1) || (l_pm[p * 2 + 1] && l_pd[p * 2 + 1] == m1);
    }

    // wave-0 per-step input gather: sentinel polls (proj may still be running
    // during the first ~10us); 1 attempt once produced. Overlaps wave-3 poll.
    float xg0 = 0, xg1 = 0, xg2 = 0, xa0 = 0;
    if (tid < 64) {
      const int jj = tid & 15;
      const float* pXg = Xg + (size_t)e * G3 + j0 + jj;
      const float* pXa = Xa + (size_t)e * H_DIM + j0 + jj;
      unsigned v0, v1, v2, v3;
      POLL4(v0, v1, v2, v3, pXg, pXg + 512, pXg + 1024, pXa, tid < 16);
      xg0 = __uint_as_float(v0);
      xg1 = __uint_as_float(v1);
      xg2 = __uint_as_float(v2);
      xa0 = __uint_as_float(v3);
    }

    // ======== wave 3: THE gather phase (sole remote reader, R11-proven) ========
    float wg0 = 0, wg1 = 0, wg2 = 0;
    if (tid >= 192) {
      const int lane = tid - 192;
      int sA = -1, sB = -1;
      if (conse) {
        if (l_cm[e * 2] && !fresh0) sA = 0;
        if (l_cm[e * 2 + 1] && !fresh1) { if (sA < 0) sA = 1; else sB = 1; }
      }
      if (e > 0) {
        const float* hrow = Hbuf + (size_t)p * H_DIM;
        u32x4v a, b;
        int gd = 0;
        do { mload16x2(hrow + lane * 4, hrow + 256 + lane * 4, a, b); }
        while ((sent4(a) || sent4(b)) && ++gd < WDOG);
        *(u32x4v*)&h1s[lane * 4] = a;
        *(u32x4v*)&h1s[256 + lane * 4] = b;
      }
      // stale skip-rows: available since >=2 steps; usually 1 attempt
      for (int k = 0; k < 2; ++k) {
        int sk = (k == 0) ? sA : sB;
        if (sk >= 0) {
          const float* srow = store + (size_t)l_ci[e * 2 + sk] * H_DIM;
          u32x4v s0, s1;
          int gd = 0;
          do { mload16x2(srow + lane * 4, srow + 256 + lane * 4, s0, s1); }
          while ((sent4(s0) || sent4(s1)) && ++gd < WDOG);
          *(u32x4v*)&cins[par][sk][lane * 4] = s0;
          *(u32x4v*)&cins[par][sk][256 + lane * 4] = s1;
        }
      }
      // Wgx gather for ct finalize (sentinel poll; ready after ~10us warmup)
      if (prodp && lane < 32) {
        int k = lane >> 4, jj = lane & 15, r = p * 2 + k;
        const float* pW = Wgx + (size_t)r * G3 + j0 + jj;
        unsigned v0, v1, v2;
        POLL3(v0, v1, v2, pW, pW + 512, pW + 1024, lane < 32);
        wg0 = __uint_as_float(v0);
        wg1 = __uint_as_float(v1);
        wg2 = __uint_as_float(v2);
      } else if (prodp) {
        unsigned v0, v1, v2;
        const float* pW = Wgx + (size_t)(p * 2) * G3 + j0;
        POLL3(v0, v1, v2, pW, pW + 512, pW + 1024, false);  // lanes 32-63 keep wave converged
      }
    }
    __syncthreads();  // syncA: h1s + stale cins + inputs ready

    if (prodp) {
      // wgates first: they gate the ct -> fresh-alpha chain
      if (tid < 192) {
        const float* vecp = h1s;
        float4 q = {0.f, 0.f, 0.f, 0.f};
        REP32(DOTB1)
        DOT_FIN(ds_wg[dcol], tid)
      }
      __syncthreads();  // s1a: ds_wg ready
      if (tid < 192) {
        const float* vecp = h1s;
        float4 q = {0.f, 0.f, 0.f, 0.f};
        REP32(DOTA1)
        DOT_FIN(ds_g[dcol], tid)
      } else {
        const int lane = tid - 192;
        if (lane < 32) {  // finalize + publish word cells for words starting at p
          int k = lane >> 4, jj = lane & 15, r = p * 2 + k;
          if (l_pm[r]) {
            float f2 = wg0 + ds_wg[jj];
            float i2 = wg1 + ds_wg[16 + jj];
            float g2 = wg2 + ds_wg[32 + jj];
            float ct = sigf(f2) * prevc1[jj] + sigf(i2) * tanhfast(g2);
            __hip_atomic_store(&store[(size_t)l_pd[r] * H_DIM + j0 + jj], ct,
                               __ATOMIC_RELAXED, SCOPE_AGENT);
          }
        }
      }
      __syncthreads();  // s1b: ds_g ready; ct stores issued
      if (conse && tid >= 192) {
        const int lane = tid - 192;
        for (int k = 0; k < 2; ++k) {  // fresh rows: poll the just-published ct
          bool fr = (k == 0) ? fresh0 : fresh1;
          if (l_cm[e * 2 + k] && fr) {
            const float* srow = store + (size_t)l_ci[e * 2 + k] * H_DIM;
            u32x4v s0, s1;
            int gd = 0;
            do { mload16x2(srow + lane * 4, srow + 256 + lane * 4, s0, s1); }
            while ((sent4(s0) || sent4(s1)) && ++gd < WDOG);
            *(u32x4v*)&cins[par][k][lane * 4] = s0;
            *(u32x4v*)&cins[par][k][256 + lane * 4] = s1;
          }
        }
        ALPHA_DOT(0);
        ALPHA_DOT(1);
      }
      __syncthreads();  // s2: ds_a + cins ready
    } else {
      if (tid < 192) {
        const float* vecp = h1s;
        float4 q = {0.f, 0.f, 0.f, 0.f};
        REP32(DOTA1)
        DOT_FIN(ds_g[dcol], tid)
      } else if (conse) {
        const int lane = tid - 192;
        ALPHA_DOT(0);
        ALPHA_DOT(1);
      }
      __syncthreads();  // sync1: ds_g (+ds_a) ready
    }

    // ---- elementwise combine for owned H-chunk (wave 0, lanes 0..15)
    if (tid < 16) {
      int j = j0 + tid;
      float ipre = xg0 + ds_g[tid];
      float opre = xg1 + ds_g[16 + tid];
      float gpre = xg2 + ds_g[32 + tid];
      float iv = sigf(ipre), ov = sigf(opre), gv = tanhfast(gpre);
      float c1;
      if (conse) {
        float ei = __expf(iv);
        float asum = ei, csum = gv * ei;
#pragma unroll
        for (int k = 0; k < 2; ++k) {
          if (l_cm[e * 2 + k]) {
            float apre = xa0 + ds_a[k * CH + tid];
            float al = __expf(sigf(apre));
            asum += al;
            csum += cins[par][k][j] * al;
          }
        }
        c1 = csum / asum;
      } else {
        c1 = (1.f - iv) * prevc1[tid] + iv * gv;
      }
      float h1 = ov * tanhfast(c1);
      prevc1[tid] = c1;
      // publish h FIRST (it gates every other WG), then output stores
      __hip_atomic_store(&Hbuf[(size_t)e * H_DIM + j], h1, __ATOMIC_RELAXED, SCOPE_AGENT);
      outh[(size_t)e * H_DIM + j] = h1;
      outc[(size_t)e * H_DIM + j] = c1;
    }
    // no end-of-step barrier: next step's poll gates everyone on h(e)
  }
}

extern "C" void kernel_launch(void* const* d_in, const int* in_sizes, int n_in,
                              void* d_out, int out_size, void* d_ws, size_t ws_size,
                              hipStream_t stream) {
  const float* x    = (const float*)d_in[0];
  const float* emb  = (const float*)d_in[1];
  const float* Wih  = (const float*)d_in[2];
  const float* Whh  = (const float*)d_in[3];
  const float* bias = (const float*)d_in[4];
  const float* aWih = (const float*)d_in[5];
  const float* aWhh = (const float*)d_in[6];
  const float* ab   = (const float*)d_in[7];
  const float* wWih = (const float*)d_in[8];
  const float* wWhh = (const float*)d_in[9];
  const float* wb   = (const float*)d_in[10];
  const int* prod_word = (const int*)d_in[11];
  const int* prod_dest = (const int*)d_in[12];
  const int* prod_mask = (const int*)d_in[13];
  const int* cons_idx  = (const int*)d_in[14];
  const int* cons_mask = (const int*)d_in[15];

  float* ws    = (float*)d_ws;
  float* Xg    = ws;                          // 512*1536  (sentinel)
  float* Xa    = Xg + 512 * 1536;             // 512*512   (sentinel)
  float* Wgx   = Xa + 512 * 512;              // 1024*1536 (sentinel)
  float* Hbuf  = Wgx + 1024 * 1536;           // 512*512   (sentinel)
  float* store = Hbuf + 512 * 512;            // 341*512   (sentinel)
  size_t nfl = (size_t)512 * 1536 + 512 * 512 + 1024 * 1536 + 512 * 512 + 341 * 512;
  if (ws_size < nfl * 4) return;

  // poison ALL sentinel-synced regions every launch (graph-replay safe)
  hipMemsetAsync(Xg, 0xFF, nfl * sizeof(float), stream);

  fused_all<<<dim3(NWG + NPRJ), dim3(NT), 0, stream>>>(
      x, emb, Wih, bias, aWih, ab, wWih, wb,
      Whh, aWhh, wWhh,
      prod_word, prod_mask, prod_dest, cons_idx, cons_mask,
      Xg, Xa, Wgx, Hbuf, store, (float*)d_out);
}

// Round 16
// 1957.243 us; speedup vs baseline: 6.8232x; 1.0998x over previous
//
#include <hip/hip_runtime.h>
#include <stdint.h>

// LatticeLSTM on MI355X, round 16 == round 11 verbatim (proven best: 1955us
// total, 1885us lattice, absmax 3.9e-3). R12-R15 explored past this point and
// all regressed or failed:
//   R12/R13 ping-pong polling: compiler register-rename hazard on split
//            issue/wait inline asm -- not implementable safely at HIP level.
//   R14 thread-level proj fusion: blew the 512-reg unified VGPR/AGPR budget,
//            weight spill (WRITE_SIZE 3.75->12.2MB), 13.4ms.
//   R15 block-level proj fusion: serial sc1 poll windows replaced hidden
//            cached loads, +270us.
// Structural floor: 682 dependent cross-die visibility events (512 h
// broadcasts + 170 fresh-ct handoffs) x ~2.76us MALL store->observe latency
// = 1882us, invariant across 8 sync designs (flags/sentinels/consolidation/
// pipelining; DVFS and read-storm falsified by direct experiment; same-XCD
// L2 messaging unreachable from HIP -- agent stores bypass local L2).

#define T_LEN 512
#define H_DIM 512
#define G3    1536
#define NWG   32
#define NT    256
#define CH    16
#define SENTU 0xFFFFFFFFu
#define WDOG  (1 << 17)
#define SCOPE_AGENT __HIP_MEMORY_SCOPE_AGENT

typedef unsigned u32x4v __attribute__((ext_vector_type(4)));

__device__ __forceinline__ float sigf(float x) { return 1.0f / (1.0f + __expf(-x)); }
__device__ __forceinline__ float tanhfast(float x) {
  x = fminf(fmaxf(x, -15.f), 15.f);
  float t = __expf(2.f * x);
  return (t - 1.f) / (t + 1.f);
}

// two pipelined 16B agent-scope loads, one vmcnt window
__device__ __forceinline__ void mload16x2(const float* p0, const float* p1,
                                          u32x4v& a, u32x4v& b) {
  asm volatile("global_load_dwordx4 %0, %2, off sc1\n\t"
               "global_load_dwordx4 %1, %3, off sc1\n\t"
               "s_waitcnt vmcnt(0)"
               : "=&v"(a), "=&v"(b) : "v"(p0), "v"(p1) : "memory");
}
__device__ __forceinline__ bool sent4(u32x4v v) {
  return v.x == SENTU || v.y == SENTU || v.z == SENTU || v.w == SENTU;
}

#define REP32(F) F(0) F(1) F(2) F(3) F(4) F(5) F(6) F(7) F(8) F(9) F(10) F(11) \
                 F(12) F(13) F(14) F(15) F(16) F(17) F(18) F(19) F(20) F(21) F(22) \
                 F(23) F(24) F(25) F(26) F(27) F(28) F(29) F(30) F(31)

#define DECLW(u) float4 wA##u = {0.f,0.f,0.f,0.f}, wB##u = {0.f,0.f,0.f,0.f};

#define LDA1(u) wA##u = make_float4(srcA[(size_t)(ks4 + u*16 + 0) * ldA + gA],  \
                                    srcA[(size_t)(ks4 + u*16 + 1) * ldA + gA],  \
                                    srcA[(size_t)(ks4 + u*16 + 2) * ldA + gA],  \
                                    srcA[(size_t)(ks4 + u*16 + 3) * ldA + gA]);
#define LDB1(u) wB##u = make_float4(srcB[(size_t)(ks4 + u*16 + 0) * (size_t)G3 + gA], \
                                    srcB[(size_t)(ks4 + u*16 + 1) * (size_t)G3 + gA], \
                                    srcB[(size_t)(ks4 + u*16 + 2) * (size_t)G3 + gA], \
                                    srcB[(size_t)(ks4 + u*16 + 3) * (size_t)G3 + gA]);

#define DOTA1(u) { float4 hv = *(const float4*)&vecp[ks4 + u*16];                \
                   q.x += hv.x*wA##u.x; q.y += hv.y*wA##u.y;                     \
                   q.z += hv.z*wA##u.z; q.w += hv.w*wA##u.w; }
#define DOTB1(u) { float4 hv = *(const float4*)&vecp[ks4 + u*16];                \
                   q.x += hv.x*wB##u.x; q.y += hv.y*wB##u.y;                     \
                   q.z += hv.z*wB##u.z; q.w += hv.w*wB##u.w; }
#define DOT_FIN(dst, g) { float acc = (q.x + q.y) + (q.z + q.w);                 \
                          acc += __shfl_down(acc, 2); acc += __shfl_down(acc, 1);\
                          if (((g) & 3) == 0) dst = acc; }

// wave-3: gather skip-cell row k (512 floats) into cins[par][k]; 2x16B/lane,
// data-sentinel poll (1 iter when stale, spins when fresh).
#define STAGE16(k)  do {                                                         \
    const float* row_ = store + (size_t)l_ci[e * 2 + (k)] * H_DIM;               \
    u32x4v r0_, r1_;                                                             \
    int gd_ = 0;                                                                 \
    do { mload16x2(row_ + lane * 4, row_ + 256 + lane * 4, r0_, r1_); }          \
    while ((sent4(r0_) || sent4(r1_)) && ++gd_ < WDOG);                          \
    *(u32x4v*)&cins[par][k][lane * 4] = r0_;                                     \
    *(u32x4v*)&cins[par][k][256 + lane * 4] = r1_;                               \
  } while (0)

#define ALPHA_DOT(k)  do {                                                       \
    if (l_cm[e * 2 + (k)]) {                                                     \
      asm volatile("s_waitcnt lgkmcnt(0)" ::: "memory");                         \
      __builtin_amdgcn_sched_barrier(0);                                         \
      const float* vecp = &cins[par][k][0];                                      \
      float4 q = {0.f, 0.f, 0.f, 0.f};                                           \
      REP32(DOTA1)                                                               \
      DOT_FIN(ds_a[(k) * CH + dcol], lane)                                       \
    }                                                                            \
  } while (0)

// ---------------- fused input projections ----------------
__global__ __launch_bounds__(256) void proj_fused(
    const float* __restrict__ x, const float* __restrict__ Wih, const float* __restrict__ bias,
    const float* __restrict__ aWih, const float* __restrict__ ab,
    const float* __restrict__ emb, const float* __restrict__ wWih, const float* __restrict__ wb,
    const int* __restrict__ prod_word,
    float* __restrict__ Xg, float* __restrict__ Xa, float* __restrict__ Wgx) {
  const int b = blockIdx.x;
  const float *A, *W, *bi;
  float* out;
  const int* gather = nullptr;
  int rt, N, cb;
  if (b < 96)       { A = x;   W = Wih;  bi = bias; out = Xg;  N = 1536; rt = (b / 6) * 32;        cb = (b % 6) * 256; }
  else if (b < 128) { int bb = b - 96;  A = x;   W = aWih; bi = ab; out = Xa;  N = 512;  rt = (bb / 2) * 32; cb = (bb % 2) * 256; }
  else              { int bb = b - 128; A = emb; W = wWih; bi = wb; out = Wgx; N = 1536; gather = prod_word; rt = (bb / 6) * 32; cb = (bb % 6) * 256; }
  __shared__ float As[32][256];
  const int tid = threadIdx.x;
  for (int rr = 0; rr < 32; ++rr) {
    int r = rt + rr;
    int src = gather ? gather[r] : r;
    As[rr][tid] = A[(long)src * 256 + tid];
  }
  __syncthreads();
  const int c = cb + tid;
  float acc[32];
#pragma unroll
  for (int rr = 0; rr < 32; ++rr) acc[rr] = 0.f;
#pragma unroll 4
  for (int k = 0; k < 256; ++k) {
    float wv = W[(long)k * N + c];
#pragma unroll
    for (int rr = 0; rr < 32; ++rr) acc[rr] += As[rr][k] * wv;
  }
  float bv = bi[c];
  for (int rr = 0; rr < 32; ++rr) out[(long)(rt + rr) * N + c] = acc[rr] + bv;
}

// ---------------- sequential lattice scan ----------------
__global__ __attribute__((amdgpu_flat_work_group_size(NT, NT), amdgpu_waves_per_eu(1, 1)))
void lattice_seq(
    const float* __restrict__ Whh, const float* __restrict__ aWhh, const float* __restrict__ wWhh,
    const float* __restrict__ Xg, const float* __restrict__ Xa, const float* __restrict__ Wgx,
    const int* __restrict__ prod_mask, const int* __restrict__ prod_dest,
    const int* __restrict__ cons_idx,  const int* __restrict__ cons_mask,
    float* __restrict__ Hbuf,     // T x 512, memset 0xFF (sentinel)
    float* __restrict__ store,    // (M+1) x 512, memset 0xFF (sentinel)
    float* __restrict__ out)      // hs at [0,T*H), cs at [T*H, 2*T*H)
{
  const int tid = threadIdx.x;
  const int w = blockIdx.x;
  const int j0 = w * CH;
  float* outh = out;
  float* outc = out + (size_t)T_LEN * H_DIM;

  __shared__ float h1s[H_DIM];
  __shared__ float prevc1[CH];
  __shared__ float ds_g[3 * CH];
  __shared__ float ds_wg[3 * CH];
  __shared__ float ds_a[2 * CH];
  __shared__ float cins[2][2][H_DIM];   // [step parity][word slot]
  __shared__ int l_pm[T_LEN * 2], l_pd[T_LEN * 2], l_ci[T_LEN * 2], l_cm[T_LEN * 2];

  for (int i = tid; i < T_LEN * 2; i += NT) {
    l_pm[i] = prod_mask[i];
    l_pd[i] = prod_dest[i];
    l_ci[i] = cons_idx[i];
    l_cm[i] = cons_mask[i];
  }

  // roles: tid<192 -> Whh (wA) + wWhh (wB), 48 cols x 4-deep;
  //        tid>=192 (wave 3) -> aWhh (wA), 16 cols x 4-deep; ALSO sole poller.
  int dcol, ks4;
  if (tid < 192) { dcol = tid >> 2; ks4 = (tid & 3) << 2; }
  else { int lane = tid - 192; dcol = lane >> 2; ks4 = (lane & 3) << 2; }

  REP32(DECLW)
  if (tid < 192) {
    const float* srcA = Whh;
    const float* srcB = wWhh;
    const size_t ldA = G3;
    const int gA = (dcol >> 4) * 512 + j0 + (dcol & 15);
    REP32(LDA1)
    REP32(LDB1)
  } else {
    const float* srcA = aWhh;
    const size_t ldA = H_DIM;
    const int gA = j0 + dcol;
    REP32(LDA1)
  }

  ((float2*)h1s)[tid] = make_float2(0.f, 0.f);
  if (tid < CH) prevc1[tid] = 0.f;
  __syncthreads();

  for (int e = 0; e < T_LEN; ++e) {
    const int p = e - 1;
    const bool prodp = (p >= 0) && ((l_pm[p * 2] | l_pm[p * 2 + 1]) != 0);
    const bool conse = (l_cm[e * 2] | l_cm[e * 2 + 1]) != 0;
    const int par = e & 1;

    // freshness: a consumed row is fresh iff produced at step p
    bool fresh0 = false, fresh1 = false;
    if (conse && prodp) {
      int m0 = l_ci[e * 2], m1 = l_ci[e * 2 + 1];
      fresh0 = (l_pm[p * 2] && l_pd[p * 2] == m0) || (l_pm[p * 2 + 1] && l_pd[p * 2 + 1] == m0);
      fresh1 = (l_pm[p * 2] && l_pd[p * 2] == m1) || (l_pm[p * 2 + 1] && l_pd[p * 2 + 1] == m1);
    }

    // wave-0 per-step input prefetch (own vmcnt domain; waited only at use)
    float xg0 = 0, xg1 = 0, xg2 = 0, xa0 = 0;
    if (tid < 16) {
      int j = j0 + tid;
      xg0 = Xg[(size_t)e * G3 + j];
      xg1 = Xg[(size_t)e * G3 + 512 + j];
      xg2 = Xg[(size_t)e * G3 + 1024 + j];
      xa0 = Xa[(size_t)e * H_DIM + j];
    }

    // ======== wave 3: THE gather phase (sole remote reader) ========
    float wg0 = 0, wg1 = 0, wg2 = 0;
    if (tid >= 192) {
      const int lane = tid - 192;
      if (prodp && lane < 32) {  // Wgx prefetch for ct finalize
        int k = lane >> 4, jj = lane & 15, r = p * 2 + k;
        wg0 = Wgx[(size_t)r * G3 + j0 + jj];
        wg1 = Wgx[(size_t)r * G3 + 512 + j0 + jj];
        wg2 = Wgx[(size_t)r * G3 + 1024 + j0 + jj];
      }
      // stale rows (available since >=2 steps): usually 1 iteration
      if (conse) {
        if (l_cm[e * 2] && !fresh0) STAGE16(0);
        if (l_cm[e * 2 + 1] && !fresh1) STAGE16(1);
      }
      // h1[e-1] gather: 2x dwordx4 per lane, one vmcnt window per attempt
      if (e > 0) {
        const float* hrow = Hbuf + (size_t)p * H_DIM;
        u32x4v a, b;
        int gd = 0;
        do { mload16x2(hrow + lane * 4, hrow + 256 + lane * 4, a, b); }
        while ((sent4(a) || sent4(b)) && ++gd < WDOG);
        *(u32x4v*)&h1s[lane * 4] = a;
        *(u32x4v*)&h1s[256 + lane * 4] = b;
      }
    }
    __syncthreads();  // syncA: h1s (+ stale cins) ready

    if (prodp) {
      // wgates first: they gate the ct -> fresh-alpha chain
      if (tid < 192) {
        const float* vecp = h1s;
        float4 q = {0.f, 0.f, 0.f, 0.f};
        REP32(DOTB1)
        DOT_FIN(ds_wg[dcol], tid)
      }
      __syncthreads();  // s1a: ds_wg ready
      if (tid < 192) {
        const float* vecp = h1s;
        float4 q = {0.f, 0.f, 0.f, 0.f};
        REP32(DOTA1)
        DOT_FIN(ds_g[dcol], tid)
      } else {
        const int lane = tid - 192;
        if (lane < 32) {  // finalize + publish word cells for words starting at p
          int k = lane >> 4, jj = lane & 15, r = p * 2 + k;
          if (l_pm[r]) {
            float f2 = wg0 + ds_wg[jj];
            float i2 = wg1 + ds_wg[16 + jj];
            float g2 = wg2 + ds_wg[32 + jj];
            float ct = sigf(f2) * prevc1[jj] + sigf(i2) * tanhfast(g2);
            __hip_atomic_store(&store[(size_t)l_pd[r] * H_DIM + j0 + jj], ct,
                               __ATOMIC_RELAXED, SCOPE_AGENT);
          }
        }
      }
      __syncthreads();  // s1b: ds_g ready; ct stores issued
      if (conse && tid >= 192) {
        const int lane = tid - 192;
        if (l_cm[e * 2] && fresh0) STAGE16(0);
        if (l_cm[e * 2 + 1] && fresh1) STAGE16(1);
        ALPHA_DOT(0);
        ALPHA_DOT(1);
      }
      __syncthreads();  // s2: ds_a + cins ready
    } else {
      if (tid < 192) {
        const float* vecp = h1s;
        float4 q = {0.f, 0.f, 0.f, 0.f};
        REP32(DOTA1)
        DOT_FIN(ds_g[dcol], tid)
      } else if (conse) {
        const int lane = tid - 192;
        ALPHA_DOT(0);
        ALPHA_DOT(1);
      }
      __syncthreads();  // sync1: ds_g (+ds_a) ready
    }

    // ---- elementwise combine for owned H-chunk (wave 0, lanes 0..15)
    if (tid < 16) {
      int j = j0 + tid;
      float ipre = xg0 + ds_g[tid];
      float opre = xg1 + ds_g[16 + tid];
      float gpre = xg2 + ds_g[32 + tid];
      float iv = sigf(ipre), ov = sigf(opre), gv = tanhfast(gpre);
      float c1;
      if (conse) {
        float ei = __expf(iv);
        float asum = ei, csum = gv * ei;
#pragma unroll
        for (int k = 0; k < 2; ++k) {
          if (l_cm[e * 2 + k]) {
            float apre = xa0 + ds_a[k * CH + tid];
            float al = __expf(sigf(apre));
            asum += al;
            csum += cins[par][k][j] * al;
          }
        }
        c1 = csum / asum;
      } else {
        c1 = (1.f - iv) * prevc1[tid] + iv * gv;
      }
      float h1 = ov * tanhfast(c1);
      prevc1[tid] = c1;
      // publish h FIRST (it gates every other WG), then output stores
      __hip_atomic_store(&Hbuf[(size_t)e * H_DIM + j], h1, __ATOMIC_RELAXED, SCOPE_AGENT);
      outh[(size_t)e * H_DIM + j] = h1;
      outc[(size_t)e * H_DIM + j] = c1;
    }
    // no end-of-step barrier: next step's poll gates everyone on h(e)
  }
}

extern "C" void kernel_launch(void* const* d_in, const int* in_sizes, int n_in,
                              void* d_out, int out_size, void* d_ws, size_t ws_size,
                              hipStream_t stream) {
  const float* x    = (const float*)d_in[0];
  const float* emb  = (const float*)d_in[1];
  const float* Wih  = (const float*)d_in[2];
  const float* Whh  = (const float*)d_in[3];
  const float* bias = (const float*)d_in[4];
  const float* aWih = (const float*)d_in[5];
  const float* aWhh = (const float*)d_in[6];
  const float* ab   = (const float*)d_in[7];
  const float* wWih = (const float*)d_in[8];
  const float* wWhh = (const float*)d_in[9];
  const float* wb   = (const float*)d_in[10];
  const int* prod_word = (const int*)d_in[11];
  const int* prod_dest = (const int*)d_in[12];
  const int* prod_mask = (const int*)d_in[13];
  const int* cons_idx  = (const int*)d_in[14];
  const int* cons_mask = (const int*)d_in[15];

  float* ws    = (float*)d_ws;
  float* Xg    = ws;                          // 512*1536
  float* Xa    = Xg + 512 * 1536;             // 512*512
  float* Wgx   = Xa + 512 * 512;              // 1024*1536
  float* Hbuf  = Wgx + 1024 * 1536;           // 512*512   (sentinel)
  float* store = Hbuf + 512 * 512;            // 341*512   (sentinel)
  size_t need = ((size_t)512 * 1536 + 512 * 512 + 1024 * 1536 + 512 * 512 + 341 * 512) * 4;
  if (ws_size < need) return;

  // re-poison sentinel regions every launch (graph-replay deterministic)
  hipMemsetAsync(Hbuf, 0xFF, (512 * 512 + 341 * 512) * sizeof(float), stream);

  proj_fused<<<dim3(320), dim3(256), 0, stream>>>(
      x, Wih, bias, aWih, ab, emb, wWih, wb, prod_word, Xg, Xa, Wgx);

  lattice_seq<<<dim3(NWG), dim3(NT), 0, stream>>>(
      Whh, aWhh, wWhh, Xg, Xa, Wgx,
      prod_mask, prod_dest, cons_idx, cons_mask,
      Hbuf, store, (float*)d_out);
}